// Round 10
// baseline (469.137 us; speedup 1.0000x reference)
//
#include <hip/hip_runtime.h>
#include <hip/hip_bf16.h>
#include <stdint.h>

#define D_IN 4096
#define TOKENS 2048
#define NUM_LATENTS 65536
#define GROUP_MUL 4
#define IN_GROUPS 64
#define KMID 256   // k' = i*4 + m

typedef __attribute__((ext_vector_type(8))) short short8;
typedef __attribute__((ext_vector_type(4))) float f32x4;

struct alignas(8)  US4 { unsigned short v[4]; };

#define FLAT_BLOCKS 24832   // (4194304 + 2097152 + 65536) / 256

__device__ inline unsigned short f2bf(float f) {
    union { float f; unsigned u; } w{f};
    unsigned r = w.u + 0x7fffu + ((w.u >> 16) & 1u);  // RNE
    return (unsigned short)(r >> 16);
}

__device__ inline void gload_lds16(const void* g, void* l) {
    __builtin_amdgcn_global_load_lds(
        (const __attribute__((address_space(1))) void*)g,
        (__attribute__((address_space(3))) void*)l, 16, 0, 0);
}

// stage3 LDS swizzle: [y][k] bf16 rows of 512B (y now 0..31).
__device__ inline int SWZ(int y, int k) {
    return ((y << 9) + (k << 1)) ^ ((((y & 7) ^ ((y >> 3) & 7)) << 4));
}

// ------------- merged converts: w, x (vector), outer (perm), inner (transpose)
__global__ __launch_bounds__(256) void cvt_all(
    const float* __restrict__ w, const float* __restrict__ x,
    const float* __restrict__ outer, const float* __restrict__ inner,
    unsigned short* __restrict__ w_bf, unsigned short* __restrict__ x_bf,
    unsigned short* __restrict__ o_bf, unsigned short* __restrict__ it_bf) {
    __shared__ float tl[64][65];
    int blk = blockIdx.x;
    const int tid = threadIdx.x;
    if (blk >= FLAT_BLOCKS) {
        // inner[m][i][x][y] f32 -> innT[m][i][y][x^((y&7)<<3)] bf16 (pre-swizzled)
        blk -= FLAT_BLOCKS;                  // m*64+i
        const float* src = inner + (size_t)blk * 4096;
        #pragma unroll
        for (int p = 0; p < 4; ++p) {
            int idx = p * 1024 + tid * 4;
            int xx = idx >> 6, y = idx & 63;
            f32x4 v = *(const f32x4*)(src + idx);
            #pragma unroll
            for (int j = 0; j < 4; ++j) tl[xx][y + j] = v[j];
        }
        __syncthreads();
        unsigned short* dst = it_bf + (size_t)blk * 4096;
        #pragma unroll
        for (int p = 0; p < 4; ++p) {
            int idx = p * 1024 + tid * 4;
            int y = idx >> 6, x0 = idx & 63;
            US4 o;
            #pragma unroll
            for (int j = 0; j < 4; ++j) o.v[j] = f2bf(tl[x0 + j][y]);
            *(US4*)(dst + y * 64 + (x0 ^ ((y & 7) << 3))) = o;
        }
        return;
    }
    int s = blk * 256 + tid;                 // f32x4 slot
    if (s < 4194304) {                       // w
        f32x4 v = *(const f32x4*)(w + (size_t)s * 4);
        US4 o;
        #pragma unroll
        for (int j = 0; j < 4; ++j) o.v[j] = f2bf(v[j]);
        *(US4*)(w_bf + (size_t)s * 4) = o;
    } else if (s < 6291456) {                // x
        int t = s - 4194304;
        f32x4 v = *(const f32x4*)(x + (size_t)t * 4);
        US4 o;
        #pragma unroll
        for (int j = 0; j < 4; ++j) o.v[j] = f2bf(v[j]);
        *(US4*)(x_bf + (size_t)t * 4) = o;
    } else {                                 // outer: [o][m][i] -> [o][i*4+m]
        int t0 = (s - 6291456) * 4;
        int o = t0 >> 8, r = t0 & 255, m = r >> 6, i = r & 63;
        f32x4 v = *(const f32x4*)(outer + t0);
        #pragma unroll
        for (int j = 0; j < 4; ++j)
            o_bf[(o << 8) + (i + j) * 4 + m] = f2bf(v[j]);
    }
}

// ------- split-K GEMM: P[ks][tok][col] = x[ks-half] @ W^T[ks-half] ---------
// grid 1024 = 512 tiles x 2 K-halves. BK=32, 3 LDS buffers (48KB -> 3 blk/CU),
// depth-2 prefetch with counted vmcnt(4). Swapped MFMA: D=[col][tok].
__global__ __launch_bounds__(256, 4) void gemm_splitk(
    const unsigned short* __restrict__ A,   // x_bf  [2048][4096]
    const unsigned short* __restrict__ B,   // w_bf  [4096][4096]
    float* __restrict__ P)                  // [2][2048][4096] f32
{
    __shared__ unsigned short smem[24576];  // 3 bufs x (A 4096 + B 4096 elems)

    const int tid = threadIdx.x;
    const int lane = tid & 63;
    const int w = tid >> 6;
    const int wm = w >> 1, wn = w & 1;
    int bx = blockIdx.x;
    const int logical = (bx & 7) * 128 + (bx >> 3);   // XCD: 4 n-panels resident
    const int ks = logical & 1;
    const int tile = logical >> 1;
    const int m0 = (tile & 15) * 128;
    const int n0 = (tile >> 4) * 128;
    const int kb = ks * 2048;

    const int lr = lane & 15;
    const int hi = lane >> 4;

    f32x4 acc[4][4] = {};

    // LDS[row][u] holds global (row, u ^ (row&3)); u = 16B unit 0..3 of 64B row
    auto STAGE = [&](int buf, int k0) {
        #pragma unroll
        for (int c = 0; c < 2; ++c) {
            int f = c * 2048 + tid * 8;     // elem in 128x32 tile
            int r = f >> 5;
            int colsw = ((((f >> 3) & 3) ^ (r & 3)) << 3);
            gload_lds16(A + (size_t)(m0 + r) * D_IN + k0 + colsw, smem + buf * 8192 + f);
            gload_lds16(B + (size_t)(n0 + r) * D_IN + k0 + colsw, smem + buf * 8192 + 4096 + f);
        }
    };
    auto COMPUTE = [&](int buf) {
        const unsigned short* as = smem + buf * 8192;
        const unsigned short* bs = as + 4096;
        short8 a[4], b[4];
        #pragma unroll
        for (int mi = 0; mi < 4; ++mi) {
            int row = wm * 64 + mi * 16 + lr;
            a[mi] = *(const short8*)(as + (row << 5) + ((hi ^ (row & 3)) << 3));
        }
        #pragma unroll
        for (int ni = 0; ni < 4; ++ni) {
            int row = wn * 64 + ni * 16 + lr;
            b[ni] = *(const short8*)(bs + (row << 5) + ((hi ^ (row & 3)) << 3));
        }
        __builtin_amdgcn_s_setprio(1);
        #pragma unroll
        for (int mi = 0; mi < 4; ++mi)
            #pragma unroll
            for (int ni = 0; ni < 4; ++ni)   // swapped: D=[col][tok]
                acc[mi][ni] = __builtin_amdgcn_mfma_f32_16x16x32_bf16(b[ni], a[mi], acc[mi][ni], 0, 0, 0);
        __builtin_amdgcn_s_setprio(0);
    };

    STAGE(0, kb);
    STAGE(1, kb + 32);
    int bcur = 0, bn2 = 2;
    #pragma unroll 1
    for (int t = 0; t < 64; ++t) {
        if (t < 63) { asm volatile("s_waitcnt vmcnt(4)" ::: "memory"); }
        else        { asm volatile("s_waitcnt vmcnt(0)" ::: "memory"); }
        __builtin_amdgcn_s_barrier();
        __builtin_amdgcn_sched_barrier(0);
        if (t < 62) STAGE(bn2, kb + (t + 2) * 32);   // overwrites buf of COMPUTE(t-1)
        COMPUTE(bcur);
        __builtin_amdgcn_sched_barrier(0);
        bcur = (bcur == 2) ? 0 : bcur + 1;
        bn2  = (bn2 == 2) ? 0 : bn2 + 1;
    }

    // write f32 partials, 16B coalesced
    float* pb = P + (size_t)ks * 8388608;
    #pragma unroll
    for (int ni = 0; ni < 4; ++ni) {
        int col0 = n0 + wn * 64 + ni * 16 + hi * 4;
        #pragma unroll
        for (int mi = 0; mi < 4; ++mi) {
            int tok = m0 + wm * 64 + mi * 16 + lr;
            __builtin_nontemporal_store(acc[mi][ni], (f32x4*)(pb + (size_t)tok * 4096 + col0));
        }
    }
}

// ------- h2t: h = P0+P1+bias (bf16, LDS) -> t[b][i*4+m][y] -----------------
// grid 1024: 64-token x 128-col tiles. LDS 32KB (h 16 + inn 16) -> 4 blk/CU.
__global__ __launch_bounds__(256) void h2t(
    const float* __restrict__ P,            // [2][2048][4096] f32
    const float* __restrict__ bias,
    const unsigned short* __restrict__ IT,  // innT [4][64][64][64] bf16, x pre-swizzled
    unsigned short* __restrict__ T)         // [2048][256][64] bf16
{
    __shared__ unsigned short smem[16384];  // h [0..8191] | inn [8192..16383]
    unsigned short* inn = smem + 8192;
    const int tid = threadIdx.x;
    const int lane = tid & 63;
    const int w = tid >> 6;
    const int wm = w >> 1, wn = w & 1;      // token-half, i_loc
    const int bx = blockIdx.x;
    const int m0 = (bx & 31) * 64;          // token base
    const int n0 = (bx >> 5) * 128;         // col base
    const int i0 = n0 >> 6;

    const int lr = lane & 15;
    const int hi = lane >> 4;
    const int lk = hi * 8;

    // prefetch inn for m=0
    #pragma unroll
    for (int c = 0; c < 4; ++c) {
        int e = c * 2048 + tid * 8;
        int i_l = e >> 12, rem = e & 4095;
        gload_lds16(IT + ((size_t)(i0 + i_l) << 12) + rem, inn + e);
    }

    // merge partials + bias -> swizzled h in LDS
    #pragma unroll
    for (int it = 0; it < 8; ++it) {
        int idx = it * 1024 + tid * 4;
        int r = idx >> 7, c = idx & 127;
        f32x4 p0 = __builtin_nontemporal_load((const f32x4*)(P + (size_t)(m0 + r) * 4096 + n0 + c));
        f32x4 p1 = __builtin_nontemporal_load((const f32x4*)(P + 8388608 + (size_t)(m0 + r) * 4096 + n0 + c));
        f32x4 bv = *(const f32x4*)(bias + n0 + c);
        US4 o;
        #pragma unroll
        for (int j = 0; j < 4; ++j) o.v[j] = f2bf(p0[j] + p1[j] + bv[j]);
        *(US4*)(smem + r * 128 + (c ^ ((r & 7) << 3))) = o;
    }

    for (int m = 0; m < 4; ++m) {
        asm volatile("s_waitcnt vmcnt(0)" ::: "memory");
        __syncthreads();   // inn m ready; h ready (m==0)

        f32x4 acc2[2][4] = {};
        #pragma unroll
        for (int kk = 0; kk < 2; ++kk) {
            short8 a[2], b2[4];
            #pragma unroll
            for (int mi = 0; mi < 2; ++mi) {
                int tok = wm * 32 + mi * 16 + lr;
                a[mi] = *(const short8*)(smem + tok * 128 + ((wn * 64 + kk * 32 + lk) ^ ((tok & 7) << 3)));
            }
            #pragma unroll
            for (int ni = 0; ni < 4; ++ni) {
                int y = ni * 16 + lr;
                b2[ni] = *(const short8*)(inn + wn * 4096 + y * 64 + ((kk * 32 + lk) ^ ((y & 7) << 3)));
            }
            #pragma unroll
            for (int mi = 0; mi < 2; ++mi)
                #pragma unroll
                for (int ni = 0; ni < 4; ++ni)   // swapped: D=[y][tok]
                    acc2[mi][ni] = __builtin_amdgcn_mfma_f32_16x16x32_bf16(b2[ni], a[mi], acc2[mi][ni], 0, 0, 0);
        }

        const int kp = (i0 + wn) * 4 + m;
        #pragma unroll
        for (int mi = 0; mi < 2; ++mi) {
            int tok = m0 + wm * 32 + mi * 16 + lr;
            unsigned short* trow = T + ((size_t)tok * KMID + kp) * 64;
            #pragma unroll
            for (int ni = 0; ni < 4; ++ni) {
                int y0 = ni * 16 + hi * 4;
                US4 o;
                #pragma unroll
                for (int j = 0; j < 4; ++j) o.v[j] = f2bf(acc2[mi][ni][j]);
                *(US4*)(trow + y0) = o;
            }
        }
        __syncthreads();   // inn consumed
        if (m < 3) {
            #pragma unroll
            for (int c = 0; c < 4; ++c) {
                int e = c * 2048 + tid * 8;
                int i_l = e >> 12, rem = e & 4095;
                gload_lds16(IT + ((size_t)((m + 1) * 64 + i0 + i_l) << 12) + rem, inn + e);
            }
        }
    }
}

// ------- stage 3: out[b][o][y] = sum_k outerB[o][k] * t[b][k][y] -----------
// grid 4096 = 2048 tokens x 2 y-halves; 512 thr, acc[2][8] -> 4 waves/SIMD,
// 2 blocks/CU. Each block stages only its 32-y half of t_b (16KB, disjoint).
__global__ __launch_bounds__(512, 4) void stage3(
    const unsigned short* __restrict__ T,   // [2048][256][64] bf16
    const unsigned short* __restrict__ Ob,  // [1024][256] bf16
    float* __restrict__ out)                // [2048][65536] f32
{
    __shared__ char ts[16384];              // [32 y][256 k] swizzled
    const int tid = threadIdx.x;
    const int lane = tid & 63;
    const int w = tid >> 6;                 // 0..7
    const int bx = blockIdx.x;
    const int logical = (bx & 7) * 512 + (bx >> 3);   // XCD: contiguous T stream
    const int b = logical >> 1;
    const int yh = logical & 1;
    const int lr = lane & 15;
    const int hi = lane >> 4;

    // stage t_b[k][yh*32 .. +32) -> LDS [yl][k] swizzled
    {
        const unsigned short* src = T + (size_t)b * (KMID * 64) + yh * 32;
        #pragma unroll
        for (int j2 = 0; j2 < 2; ++j2) {
            int e = tid * 16 + j2 * 8;      // local elem in [32][256] (k-major count)
            int k = e >> 5, yl = e & 31;    // yl multiple of 8
            short8 v = __builtin_nontemporal_load((const short8*)(src + k * 64 + yl));
            #pragma unroll
            for (int jj = 0; jj < 8; ++jj)
                *(unsigned short*)(ts + SWZ(yl + jj, k)) = (unsigned short)v[jj];
        }
    }
    __syncthreads();

    const int o_base = w * 128;
    f32x4 acc[2][8] = {};   // [ni_y][mi_o]
    for (int kt = 0; kt < 8; ++kt) {
        short8 tf0 = *(const short8*)(ts + SWZ(lr, kt * 32 + hi * 8));
        short8 tf1 = *(const short8*)(ts + SWZ(16 + lr, kt * 32 + hi * 8));
        #pragma unroll
        for (int mi = 0; mi < 8; ++mi) {
            short8 of = *(const short8*)(Ob + ((size_t)(o_base + mi * 16 + lr) << 8) + kt * 32 + hi * 8);
            acc[0][mi] = __builtin_amdgcn_mfma_f32_16x16x32_bf16(tf0, of, acc[0][mi], 0, 0, 0);
            acc[1][mi] = __builtin_amdgcn_mfma_f32_16x16x32_bf16(tf1, of, acc[1][mi], 0, 0, 0);
        }
    }

    float* ob = out + (size_t)b * NUM_LATENTS + yh * 32;
    #pragma unroll
    for (int ni = 0; ni < 2; ++ni) {
        #pragma unroll
        for (int mi = 0; mi < 8; ++mi) {
            int o = o_base + mi * 16 + lr;
            int y = ni * 16 + hi * 4;
            __builtin_nontemporal_store(acc[ni][mi], (f32x4*)(ob + (o << 6) + y));
        }
    }
}

extern "C" void kernel_launch(void* const* d_in, const int* in_sizes, int n_in,
                              void* d_out, int out_size, void* d_ws, size_t ws_size,
                              hipStream_t stream) {
    const float* x     = (const float*)d_in[0];
    const float* pre_w = (const float*)d_in[1];
    const float* pre_b = (const float*)d_in[2];
    const float* inner = (const float*)d_in[3];
    const float* outer = (const float*)d_in[4];
    float* out = (float*)d_out;

    char* ws = (char*)d_ws;
    float* part = (float*)ws;                    ws += (size_t)2 * TOKENS * D_IN * 4;
    unsigned short* x_bf = (unsigned short*)ws;  ws += (size_t)TOKENS * D_IN * 2;
    unsigned short* w_bf = (unsigned short*)ws;  ws += (size_t)D_IN * D_IN * 2;
    unsigned short* o_bf = (unsigned short*)ws;  ws += (size_t)1024 * KMID * 2;
    unsigned short* t_bf = (unsigned short*)ws;  ws += (size_t)TOKENS * KMID * 64 * 2;
    unsigned short* it_bf = (unsigned short*)ws; ws += (size_t)GROUP_MUL * IN_GROUPS * 64 * 64 * 2;

    cvt_all<<<FLAT_BLOCKS + GROUP_MUL * IN_GROUPS, 256, 0, stream>>>(
        pre_w, x, outer, inner, w_bf, x_bf, o_bf, it_bf);

    gemm_splitk<<<1024, 256, 0, stream>>>(x_bf, w_bf, part);
    h2t<<<1024, 256, 0, stream>>>(part, pre_b, it_bf, t_bf);
    stage3<<<4096, 512, 0, stream>>>(t_bf, o_bf, out);
}

// Round 11
// 356.210 us; speedup vs baseline: 1.3170x; 1.3170x over previous
//
#include <hip/hip_runtime.h>
#include <hip/hip_bf16.h>
#include <stdint.h>

#define D_IN 4096
#define TOKENS 2048
#define NUM_LATENTS 65536
#define GROUP_MUL 4
#define IN_GROUPS 64
#define KMID 256   // k' = i*4 + m

typedef __attribute__((ext_vector_type(8))) short short8;
typedef __attribute__((ext_vector_type(4))) float f32x4;

struct alignas(8)  US4 { unsigned short v[4]; };

#define FLAT_BLOCKS 24832   // (4194304 + 2097152 + 65536) / 256

__device__ inline unsigned short f2bf(float f) {
    union { float f; unsigned u; } w{f};
    unsigned r = w.u + 0x7fffu + ((w.u >> 16) & 1u);  // RNE
    return (unsigned short)(r >> 16);
}

__device__ inline void gload_lds16(const void* g, void* l) {
    __builtin_amdgcn_global_load_lds(
        (const __attribute__((address_space(1))) void*)g,
        (__attribute__((address_space(3))) void*)l, 16, 0, 0);
}

// stage3 LDS swizzle: [y][k] bf16 rows of 512B.
// XOR ((y&7)^((y>>3)&7)) into byte bits 4..6 -> conflict-light on BOTH the
// scalar write side and the tf read side.
__device__ inline int SWZ(int y, int k) {
    return ((y << 9) + (k << 1)) ^ ((((y & 7) ^ ((y >> 3) & 7)) << 4));
}

// ------------- merged converts: w, x (vector), outer (perm), inner (transpose)
__global__ __launch_bounds__(256) void cvt_all(
    const float* __restrict__ w, const float* __restrict__ x,
    const float* __restrict__ outer, const float* __restrict__ inner,
    unsigned short* __restrict__ w_bf, unsigned short* __restrict__ x_bf,
    unsigned short* __restrict__ o_bf, unsigned short* __restrict__ it_bf) {
    __shared__ float tl[64][65];
    int blk = blockIdx.x;
    const int tid = threadIdx.x;
    if (blk >= FLAT_BLOCKS) {
        // inner[m][i][x][y] f32 -> innT[m][i][y][x^((y&7)<<3)] bf16 (pre-swizzled)
        blk -= FLAT_BLOCKS;                  // m*64+i
        const float* src = inner + (size_t)blk * 4096;
        #pragma unroll
        for (int p = 0; p < 4; ++p) {
            int idx = p * 1024 + tid * 4;
            int xx = idx >> 6, y = idx & 63;
            f32x4 v = *(const f32x4*)(src + idx);
            #pragma unroll
            for (int j = 0; j < 4; ++j) tl[xx][y + j] = v[j];
        }
        __syncthreads();
        unsigned short* dst = it_bf + (size_t)blk * 4096;
        #pragma unroll
        for (int p = 0; p < 4; ++p) {
            int idx = p * 1024 + tid * 4;
            int y = idx >> 6, x0 = idx & 63;
            US4 o;
            #pragma unroll
            for (int j = 0; j < 4; ++j) o.v[j] = f2bf(tl[x0 + j][y]);
            *(US4*)(dst + y * 64 + (x0 ^ ((y & 7) << 3))) = o;
        }
        return;
    }
    int s = blk * 256 + tid;                 // f32x4 slot
    if (s < 4194304) {                       // w
        f32x4 v = *(const f32x4*)(w + (size_t)s * 4);
        US4 o;
        #pragma unroll
        for (int j = 0; j < 4; ++j) o.v[j] = f2bf(v[j]);
        *(US4*)(w_bf + (size_t)s * 4) = o;
    } else if (s < 6291456) {                // x
        int t = s - 4194304;
        f32x4 v = *(const f32x4*)(x + (size_t)t * 4);
        US4 o;
        #pragma unroll
        for (int j = 0; j < 4; ++j) o.v[j] = f2bf(v[j]);
        *(US4*)(x_bf + (size_t)t * 4) = o;
    } else {                                 // outer: [o][m][i] -> [o][i*4+m]
        int t0 = (s - 6291456) * 4;
        int o = t0 >> 8, r = t0 & 255, m = r >> 6, i = r & 63;
        f32x4 v = *(const f32x4*)(outer + t0);
        #pragma unroll
        for (int j = 0; j < 4; ++j)
            o_bf[(o << 8) + (i + j) * 4 + m] = f2bf(v[j]);
    }
}

// ------- split-K GEMM: P[ks][tok][col] = x[ks-half] @ W^T[ks-half] ---------
// grid 1024 = 512 tiles x 2 K-halves. BK=32, 3 LDS buffers (48KB -> 3 blk/CU),
// depth-2 prefetch with counted vmcnt(4). Swapped MFMA: D=[col][tok].
__global__ __launch_bounds__(256, 4) void gemm_splitk(
    const unsigned short* __restrict__ A,   // x_bf  [2048][4096]
    const unsigned short* __restrict__ B,   // w_bf  [4096][4096]
    float* __restrict__ P)                  // [2][2048][4096] f32
{
    __shared__ unsigned short smem[24576];  // 3 bufs x (A 4096 + B 4096 elems)

    const int tid = threadIdx.x;
    const int lane = tid & 63;
    const int w = tid >> 6;
    const int wm = w >> 1, wn = w & 1;
    int bx = blockIdx.x;
    const int logical = (bx & 7) * 128 + (bx >> 3);   // XCD: 4 n-panels resident
    const int ks = logical & 1;
    const int tile = logical >> 1;
    const int m0 = (tile & 15) * 128;
    const int n0 = (tile >> 4) * 128;
    const int kb = ks * 2048;

    const int lr = lane & 15;
    const int hi = lane >> 4;

    f32x4 acc[4][4] = {};

    // LDS[row][u] holds global (row, u ^ (row&3)); u = 16B unit 0..3 of 64B row
    auto STAGE = [&](int buf, int k0) {
        #pragma unroll
        for (int c = 0; c < 2; ++c) {
            int f = c * 2048 + tid * 8;     // elem in 128x32 tile
            int r = f >> 5;
            int colsw = ((((f >> 3) & 3) ^ (r & 3)) << 3);
            gload_lds16(A + (size_t)(m0 + r) * D_IN + k0 + colsw, smem + buf * 8192 + f);
            gload_lds16(B + (size_t)(n0 + r) * D_IN + k0 + colsw, smem + buf * 8192 + 4096 + f);
        }
    };
    auto COMPUTE = [&](int buf) {
        const unsigned short* as = smem + buf * 8192;
        const unsigned short* bs = as + 4096;
        short8 a[4], b[4];
        #pragma unroll
        for (int mi = 0; mi < 4; ++mi) {
            int row = wm * 64 + mi * 16 + lr;
            a[mi] = *(const short8*)(as + (row << 5) + ((hi ^ (row & 3)) << 3));
        }
        #pragma unroll
        for (int ni = 0; ni < 4; ++ni) {
            int row = wn * 64 + ni * 16 + lr;
            b[ni] = *(const short8*)(bs + (row << 5) + ((hi ^ (row & 3)) << 3));
        }
        __builtin_amdgcn_s_setprio(1);
        #pragma unroll
        for (int mi = 0; mi < 4; ++mi)
            #pragma unroll
            for (int ni = 0; ni < 4; ++ni)   // swapped: D=[col][tok]
                acc[mi][ni] = __builtin_amdgcn_mfma_f32_16x16x32_bf16(b[ni], a[mi], acc[mi][ni], 0, 0, 0);
        __builtin_amdgcn_s_setprio(0);
    };

    STAGE(0, kb);
    STAGE(1, kb + 32);
    int bcur = 0, bn2 = 2;
    #pragma unroll 1
    for (int t = 0; t < 64; ++t) {
        if (t < 63) { asm volatile("s_waitcnt vmcnt(4)" ::: "memory"); }
        else        { asm volatile("s_waitcnt vmcnt(0)" ::: "memory"); }
        __builtin_amdgcn_s_barrier();
        __builtin_amdgcn_sched_barrier(0);
        if (t < 62) STAGE(bn2, kb + (t + 2) * 32);   // overwrites buf of COMPUTE(t-1)
        COMPUTE(bcur);
        __builtin_amdgcn_sched_barrier(0);
        bcur = (bcur == 2) ? 0 : bcur + 1;
        bn2  = (bn2 == 2) ? 0 : bn2 + 1;
    }

    // write f32 partials, 16B coalesced
    float* pb = P + (size_t)ks * 8388608;
    #pragma unroll
    for (int ni = 0; ni < 4; ++ni) {
        int col0 = n0 + wn * 64 + ni * 16 + hi * 4;
        #pragma unroll
        for (int mi = 0; mi < 4; ++mi) {
            int tok = m0 + wm * 64 + mi * 16 + lr;
            __builtin_nontemporal_store(acc[mi][ni], (f32x4*)(pb + (size_t)tok * 4096 + col0));
        }
    }
}

// ------- h2t: h = P0+P1+bias (bf16, LDS) -> t[b][i*4+m][y] -----------------
// grid 1024: 64-token x 128-col tiles. LDS 32KB (h 16 + inn 16) -> 4 blk/CU.
__global__ __launch_bounds__(256) void h2t(
    const float* __restrict__ P,            // [2][2048][4096] f32
    const float* __restrict__ bias,
    const unsigned short* __restrict__ IT,  // innT [4][64][64][64] bf16, x pre-swizzled
    unsigned short* __restrict__ T)         // [2048][256][64] bf16
{
    __shared__ unsigned short smem[16384];  // h [0..8191] | inn [8192..16383]
    unsigned short* inn = smem + 8192;
    const int tid = threadIdx.x;
    const int lane = tid & 63;
    const int w = tid >> 6;
    const int wm = w >> 1, wn = w & 1;      // token-half, i_loc
    const int bx = blockIdx.x;
    const int m0 = (bx & 31) * 64;          // token base
    const int n0 = (bx >> 5) * 128;         // col base
    const int i0 = n0 >> 6;

    const int lr = lane & 15;
    const int hi = lane >> 4;
    const int lk = hi * 8;

    // prefetch inn for m=0
    #pragma unroll
    for (int c = 0; c < 4; ++c) {
        int e = c * 2048 + tid * 8;
        int i_l = e >> 12, rem = e & 4095;
        gload_lds16(IT + ((size_t)(i0 + i_l) << 12) + rem, inn + e);
    }

    // merge partials + bias -> swizzled h in LDS
    #pragma unroll
    for (int it = 0; it < 8; ++it) {
        int idx = it * 1024 + tid * 4;
        int r = idx >> 7, c = idx & 127;
        f32x4 p0 = __builtin_nontemporal_load((const f32x4*)(P + (size_t)(m0 + r) * 4096 + n0 + c));
        f32x4 p1 = __builtin_nontemporal_load((const f32x4*)(P + 8388608 + (size_t)(m0 + r) * 4096 + n0 + c));
        f32x4 bv = *(const f32x4*)(bias + n0 + c);
        US4 o;
        #pragma unroll
        for (int j = 0; j < 4; ++j) o.v[j] = f2bf(p0[j] + p1[j] + bv[j]);
        *(US4*)(smem + r * 128 + (c ^ ((r & 7) << 3))) = o;
    }

    for (int m = 0; m < 4; ++m) {
        asm volatile("s_waitcnt vmcnt(0)" ::: "memory");
        __syncthreads();   // inn m ready; h ready (m==0)

        f32x4 acc2[2][4] = {};
        #pragma unroll
        for (int kk = 0; kk < 2; ++kk) {
            short8 a[2], b2[4];
            #pragma unroll
            for (int mi = 0; mi < 2; ++mi) {
                int tok = wm * 32 + mi * 16 + lr;
                a[mi] = *(const short8*)(smem + tok * 128 + ((wn * 64 + kk * 32 + lk) ^ ((tok & 7) << 3)));
            }
            #pragma unroll
            for (int ni = 0; ni < 4; ++ni) {
                int y = ni * 16 + lr;
                b2[ni] = *(const short8*)(inn + wn * 4096 + y * 64 + ((kk * 32 + lk) ^ ((y & 7) << 3)));
            }
            #pragma unroll
            for (int mi = 0; mi < 2; ++mi)
                #pragma unroll
                for (int ni = 0; ni < 4; ++ni)   // swapped: D=[y][tok]
                    acc2[mi][ni] = __builtin_amdgcn_mfma_f32_16x16x32_bf16(b2[ni], a[mi], acc2[mi][ni], 0, 0, 0);
        }

        const int kp = (i0 + wn) * 4 + m;
        #pragma unroll
        for (int mi = 0; mi < 2; ++mi) {
            int tok = m0 + wm * 32 + mi * 16 + lr;
            unsigned short* trow = T + ((size_t)tok * KMID + kp) * 64;
            #pragma unroll
            for (int ni = 0; ni < 4; ++ni) {
                int y0 = ni * 16 + hi * 4;
                US4 o;
                #pragma unroll
                for (int j = 0; j < 4; ++j) o.v[j] = f2bf(acc2[mi][ni][j]);
                *(US4*)(trow + y0) = o;
            }
        }
        __syncthreads();   // inn consumed
        if (m < 3) {
            #pragma unroll
            for (int c = 0; c < 4; ++c) {
                int e = c * 2048 + tid * 8;
                int i_l = e >> 12, rem = e & 4095;
                gload_lds16(IT + ((size_t)((m + 1) * 64 + i0 + i_l) << 12) + rem, inn + e);
            }
        }
    }
}

// ---------------- stage 3 (r7 structure): out[b][o][y] = sum_k Ob[o][k] t[b][k][y]
// one block per token (512 thr, 8 waves x 128 o). t^T staged in swizzled LDS.
// MFMA operands swapped (A = t^T, B = outer) -> D[y][o], f32x4 y-contig stores.
__global__ __launch_bounds__(512) void stage3(
    const unsigned short* __restrict__ T,   // [2048][256][64] bf16
    const unsigned short* __restrict__ Ob,  // [1024][256] bf16
    float* __restrict__ out)                // [2048][65536] f32
{
    __shared__ char ts[32768];
    const int tid = threadIdx.x;
    const int lane = tid & 63;
    const int w = tid >> 6;
    int bx = blockIdx.x;
    const int b = (bx & 7) * 256 + (bx >> 3);   // XCD swizzle
    const int lr = lane & 15;
    const int hi = lane >> 4;

    {
        const unsigned short* src = T + (size_t)b * (KMID * 64);
        #pragma unroll
        for (int c = 0; c < 4; ++c) {
            int e = c * 4096 + tid * 8;
            int k = e >> 6, y = e & 63;
            short8 v = __builtin_nontemporal_load((const short8*)(src + e));
            #pragma unroll
            for (int j = 0; j < 8; ++j)
                *(unsigned short*)(ts + SWZ(y + j, k)) = (unsigned short)v[j];
        }
    }
    __syncthreads();

    const int o_base = w * 128;
    f32x4 acc[4][8] = {};   // [ni_y][mi_o]
    for (int kt = 0; kt < 8; ++kt) {
        short8 tf[4], of[8];
        #pragma unroll
        for (int ni = 0; ni < 4; ++ni)
            tf[ni] = *(const short8*)(ts + SWZ(ni * 16 + lr, kt * 32 + hi * 8));
        #pragma unroll
        for (int mi = 0; mi < 8; ++mi)
            of[mi] = *(const short8*)(Ob + ((size_t)(o_base + mi * 16 + lr) << 8) + kt * 32 + hi * 8);
        #pragma unroll
        for (int ni = 0; ni < 4; ++ni)
            #pragma unroll
            for (int mi = 0; mi < 8; ++mi)
                acc[ni][mi] = __builtin_amdgcn_mfma_f32_16x16x32_bf16(tf[ni], of[mi], acc[ni][mi], 0, 0, 0);
    }

    float* ob = out + (size_t)b * NUM_LATENTS;
    #pragma unroll
    for (int ni = 0; ni < 4; ++ni) {
        #pragma unroll
        for (int mi = 0; mi < 8; ++mi) {
            int o = o_base + mi * 16 + lr;
            int y = ni * 16 + hi * 4;
            __builtin_nontemporal_store(acc[ni][mi], (f32x4*)(ob + (o << 6) + y));
        }
    }
}

extern "C" void kernel_launch(void* const* d_in, const int* in_sizes, int n_in,
                              void* d_out, int out_size, void* d_ws, size_t ws_size,
                              hipStream_t stream) {
    const float* x     = (const float*)d_in[0];
    const float* pre_w = (const float*)d_in[1];
    const float* pre_b = (const float*)d_in[2];
    const float* inner = (const float*)d_in[3];
    const float* outer = (const float*)d_in[4];
    float* out = (float*)d_out;

    char* ws = (char*)d_ws;
    float* part = (float*)ws;                    ws += (size_t)2 * TOKENS * D_IN * 4;
    unsigned short* x_bf = (unsigned short*)ws;  ws += (size_t)TOKENS * D_IN * 2;
    unsigned short* w_bf = (unsigned short*)ws;  ws += (size_t)D_IN * D_IN * 2;
    unsigned short* o_bf = (unsigned short*)ws;  ws += (size_t)1024 * KMID * 2;
    unsigned short* t_bf = (unsigned short*)ws;  ws += (size_t)TOKENS * KMID * 64 * 2;
    unsigned short* it_bf = (unsigned short*)ws; ws += (size_t)GROUP_MUL * IN_GROUPS * 64 * 64 * 2;

    cvt_all<<<FLAT_BLOCKS + GROUP_MUL * IN_GROUPS, 256, 0, stream>>>(
        pre_w, x, outer, inner, w_bf, x_bf, o_bf, it_bf);

    gemm_splitk<<<1024, 256, 0, stream>>>(x_bf, w_bf, part);
    h2t<<<1024, 256, 0, stream>>>(part, pre_b, it_bf, t_bf);
    stage3<<<2048, 512, 0, stream>>>(t_bf, o_bf, out);
}

// Round 12
// 315.361 us; speedup vs baseline: 1.4876x; 1.1295x over previous
//
#include <hip/hip_runtime.h>
#include <hip/hip_bf16.h>
#include <stdint.h>

#define D_IN 4096
#define TOKENS 2048
#define NUM_LATENTS 65536
#define GROUP_MUL 4
#define IN_GROUPS 64
#define KMID 256   // k' = i*4 + m

typedef __attribute__((ext_vector_type(8))) short short8;
typedef __attribute__((ext_vector_type(4))) float f32x4;

struct alignas(8)  US4 { unsigned short v[4]; };

#define FLAT_BLOCKS 24832   // (4194304 + 2097152 + 65536) / 256

__device__ inline unsigned short f2bf(float f) {
    union { float f; unsigned u; } w{f};
    unsigned r = w.u + 0x7fffu + ((w.u >> 16) & 1u);  // RNE
    return (unsigned short)(r >> 16);
}

__device__ inline void gload_lds16(const void* g, void* l) {
    __builtin_amdgcn_global_load_lds(
        (const __attribute__((address_space(1))) void*)g,
        (__attribute__((address_space(3))) void*)l, 16, 0, 0);
}

// stage3 LDS swizzle: [y][k] bf16 rows of 512B.
__device__ inline int SWZ(int y, int k) {
    return ((y << 9) + (k << 1)) ^ ((((y & 7) ^ ((y >> 3) & 7)) << 4));
}

// ------------- merged converts: w, x (vector), outer (perm), inner (transpose)
__global__ __launch_bounds__(256) void cvt_all(
    const float* __restrict__ w, const float* __restrict__ x,
    const float* __restrict__ outer, const float* __restrict__ inner,
    unsigned short* __restrict__ w_bf, unsigned short* __restrict__ x_bf,
    unsigned short* __restrict__ o_bf, unsigned short* __restrict__ it_bf) {
    __shared__ float tl[64][65];
    int blk = blockIdx.x;
    const int tid = threadIdx.x;
    if (blk >= FLAT_BLOCKS) {
        // inner[m][i][x][y] f32 -> innT[m][i][y][x^((y&7)<<3)] bf16 (pre-swizzled)
        blk -= FLAT_BLOCKS;                  // m*64+i
        const float* src = inner + (size_t)blk * 4096;
        #pragma unroll
        for (int p = 0; p < 4; ++p) {
            int idx = p * 1024 + tid * 4;
            int xx = idx >> 6, y = idx & 63;
            f32x4 v = *(const f32x4*)(src + idx);
            #pragma unroll
            for (int j = 0; j < 4; ++j) tl[xx][y + j] = v[j];
        }
        __syncthreads();
        unsigned short* dst = it_bf + (size_t)blk * 4096;
        #pragma unroll
        for (int p = 0; p < 4; ++p) {
            int idx = p * 1024 + tid * 4;
            int y = idx >> 6, x0 = idx & 63;
            US4 o;
            #pragma unroll
            for (int j = 0; j < 4; ++j) o.v[j] = f2bf(tl[x0 + j][y]);
            *(US4*)(dst + y * 64 + (x0 ^ ((y & 7) << 3))) = o;
        }
        return;
    }
    int s = blk * 256 + tid;                 // f32x4 slot
    if (s < 4194304) {                       // w
        f32x4 v = *(const f32x4*)(w + (size_t)s * 4);
        US4 o;
        #pragma unroll
        for (int j = 0; j < 4; ++j) o.v[j] = f2bf(v[j]);
        *(US4*)(w_bf + (size_t)s * 4) = o;
    } else if (s < 6291456) {                // x
        int t = s - 4194304;
        f32x4 v = *(const f32x4*)(x + (size_t)t * 4);
        US4 o;
        #pragma unroll
        for (int j = 0; j < 4; ++j) o.v[j] = f2bf(v[j]);
        *(US4*)(x_bf + (size_t)t * 4) = o;
    } else {                                 // outer: [o][m][i] -> [o][i*4+m]
        int t0 = (s - 6291456) * 4;
        int o = t0 >> 8, r = t0 & 255, m = r >> 6, i = r & 63;
        f32x4 v = *(const f32x4*)(outer + t0);
        #pragma unroll
        for (int j = 0; j < 4; ++j)
            o_bf[(o << 8) + (i + j) * 4 + m] = f2bf(v[j]);
    }
}

// ------- fused stage 1+2, 8-PHASE schedule (T2+T3+T4+T5) -------------------
// BM=128 BN=256 BK=64, grid 256 (16m x 16n, 1 block/CU), 512 thr = 8 waves
// (2M x 4N, wave tile 64x64, acc[4][4]). LDS: dbuf 2 x (A 16KB + B 32KB) = 96KB.
// Per K-tile: 4 phases {stage || ds_read -> bar -> lgkm0 -> prio1 8xMFMA -> bar}.
// Epilogue: h(+bias) -> LDS (64KB overlay) -> per m: inn(32KB) stage2 MFMA -> T.
__global__ __launch_bounds__(512, 2) void gemm_fused(
    const unsigned short* __restrict__ A,   // x_bf  [2048][4096]
    const unsigned short* __restrict__ B,   // w_bf  [4096][4096]
    const float* __restrict__ bias,
    const unsigned short* __restrict__ IT,  // innT [4][64][64][64] bf16, x pre-swizzled
    unsigned short* __restrict__ T)         // [2048][256][64] bf16
{
    __shared__ unsigned short smem[49152];  // 96 KB

    const int tid = threadIdx.x;
    const int lane = tid & 63;
    const int w = tid >> 6;          // 0..7
    const int wm = w >> 2;           // 0..1 : 64-token half
    const int wn = w & 3;            // 0..3 : 64-col quarter of 256
    int bx = blockIdx.x;
    const int logical = (bx & 7) * 32 + (bx >> 3);  // XCD x -> n-tiles {2x,2x+1} (4MB B = L2)
    const int m0 = (logical & 15) * 128;
    const int n0 = (logical >> 4) * 256;
    const int i0 = n0 >> 6;          // first of 4 i-groups

    const int lr = lane & 15;
    const int hi = lane >> 4;
    const int lk = hi * 8;

    f32x4 acc[4][4] = {};

    // LDS[row][u] holds global (row, u ^ (row&7)); u = 16B unit 0..7 per 128B row
    auto STAGE_A = [&](unsigned short* As, int k0) {
        #pragma unroll
        for (int c = 0; c < 2; ++c) {
            int f = c * 4096 + tid * 8;
            int r = f >> 6;
            int colsw = ((((f >> 3) & 7) ^ (r & 7)) << 3);
            gload_lds16(A + (size_t)(m0 + r) * D_IN + k0 + colsw, As + f);
        }
    };
    auto STAGE_B = [&](unsigned short* Bs, int k0, int c0) {
        #pragma unroll
        for (int c = 0; c < 2; ++c) {
            int f = (c0 + c) * 4096 + tid * 8;
            int r = f >> 6;
            int colsw = ((((f >> 3) & 7) ^ (r & 7)) << 3);
            gload_lds16(B + (size_t)(n0 + r) * D_IN + k0 + colsw, Bs + f);
        }
    };

    // prologue: stage tile 0
    STAGE_A(smem, 0);
    STAGE_B(smem + 8192, 0, 0);
    STAGE_B(smem + 8192, 0, 2);

    short8 a0, a1, a2, a3, b0, b1, b2, b3;
    #define RD_A(dst, mi, kk, as) { int row = wm * 64 + (mi) * 16 + lr; \
        dst = *(const short8*)((as) + (row << 6) + ((((kk << 2) + hi) ^ (lr & 7)) << 3)); }
    #define RD_B(dst, ni, kk, bs) { int row = wn * 64 + (ni) * 16 + lr; \
        dst = *(const short8*)((bs) + (row << 6) + ((((kk << 2) + hi) ^ (lr & 7)) << 3)); }
    #define MF(mi, ni, bb, aa) acc[mi][ni] = __builtin_amdgcn_mfma_f32_16x16x32_bf16(bb, aa, acc[mi][ni], 0, 0, 0);
    #define PHASE_TAIL \
        __builtin_amdgcn_s_barrier(); \
        asm volatile("s_waitcnt lgkmcnt(0)" ::: "memory"); \
        __builtin_amdgcn_sched_barrier(0);
    #define PHASE_END \
        __builtin_amdgcn_s_setprio(0); \
        __builtin_amdgcn_s_barrier(); \
        __builtin_amdgcn_sched_barrier(0);

    #pragma unroll 1
    for (int t = 0; t < 64; ++t) {
        unsigned short* As = smem + (t & 1) * 24576;
        unsigned short* Bs = As + 8192;
        unsigned short* Asn = smem + ((t & 1) ^ 1) * 24576;
        unsigned short* Bsn = Asn + 8192;
        const int kn = (t + 1) * 64;

        // buffer switch: staging(t) (issued during t-1) landed; all waves past old reads
        asm volatile("s_waitcnt vmcnt(0)" ::: "memory");
        __builtin_amdgcn_s_barrier();
        __builtin_amdgcn_sched_barrier(0);

        // P0: stage A(t+1) | read a*,b0,b1 kk0 | mfma ni 0..1 kk0
        if (t < 63) STAGE_A(Asn, kn);
        RD_A(a0, 0, 0, As) RD_A(a1, 1, 0, As) RD_A(a2, 2, 0, As) RD_A(a3, 3, 0, As)
        RD_B(b0, 0, 0, Bs) RD_B(b1, 1, 0, Bs)
        PHASE_TAIL
        __builtin_amdgcn_s_setprio(1);
        MF(0,0,b0,a0) MF(1,0,b0,a1) MF(2,0,b0,a2) MF(3,0,b0,a3)
        MF(0,1,b1,a0) MF(1,1,b1,a1) MF(2,1,b1,a2) MF(3,1,b1,a3)
        PHASE_END

        // P1: stage B(t+1) half1 | read b2,b3 kk0 | mfma ni 2..3 kk0
        if (t < 63) STAGE_B(Bsn, kn, 0);
        RD_B(b2, 2, 0, Bs) RD_B(b3, 3, 0, Bs)
        PHASE_TAIL
        __builtin_amdgcn_s_setprio(1);
        MF(0,2,b2,a0) MF(1,2,b2,a1) MF(2,2,b2,a2) MF(3,2,b2,a3)
        MF(0,3,b3,a0) MF(1,3,b3,a1) MF(2,3,b3,a2) MF(3,3,b3,a3)
        PHASE_END

        // P2: stage B(t+1) half2 | read a* kk1, b0,b1 kk1 | mfma ni 0..1 kk1
        if (t < 63) STAGE_B(Bsn, kn, 2);
        RD_A(a0, 0, 1, As) RD_A(a1, 1, 1, As) RD_A(a2, 2, 1, As) RD_A(a3, 3, 1, As)
        RD_B(b0, 0, 1, Bs) RD_B(b1, 1, 1, Bs)
        PHASE_TAIL
        __builtin_amdgcn_s_setprio(1);
        MF(0,0,b0,a0) MF(1,0,b0,a1) MF(2,0,b0,a2) MF(3,0,b0,a3)
        MF(0,1,b1,a0) MF(1,1,b1,a1) MF(2,1,b1,a2) MF(3,1,b1,a3)
        PHASE_END

        // P3: read b2,b3 kk1 | mfma ni 2..3 kk1
        RD_B(b2, 2, 1, Bs) RD_B(b3, 3, 1, Bs)
        PHASE_TAIL
        __builtin_amdgcn_s_setprio(1);
        MF(0,2,b2,a0) MF(1,2,b2,a1) MF(2,2,b2,a2) MF(3,2,b2,a3)
        MF(0,3,b3,a0) MF(1,3,b3,a1) MF(2,3,b3,a2) MF(3,3,b3,a3)
        PHASE_END
    }

    // ---- epilogue A: h (+bias, bf16) -> smem[0..32767], swizzled (512B rows)
    #pragma unroll
    for (int ni = 0; ni < 4; ++ni) {
        int col0 = wn * 64 + ni * 16 + hi * 4;
        f32x4 bv = *(const f32x4*)(bias + n0 + col0);
        #pragma unroll
        for (int mi = 0; mi < 4; ++mi) {
            int tok = wm * 64 + mi * 16 + lr;
            US4 o;
            #pragma unroll
            for (int j = 0; j < 4; ++j) o.v[j] = f2bf(acc[mi][ni][j] + bv[j]);
            *(US4*)(smem + tok * 256 + (col0 ^ ((tok & 7) << 3))) = o;
        }
    }

    // ---- epilogue B: per m, wave wn owns i-group i0+wn:
    // t[tok][(i0+wn)*4+m][y] = h[tok][i,:] @ innT^T
    unsigned short* inn = smem + 32768;    // 4 x 4096 elems = 32 KB
    for (int m = 0; m < 4; ++m) {
        #pragma unroll
        for (int c = 0; c < 4; ++c) {
            int e = c * 4096 + tid * 8;
            int i_l = e >> 12, rem = e & 4095;
            gload_lds16(IT + ((size_t)(m * 64 + i0 + i_l) << 12) + rem, inn + e);
        }
        asm volatile("s_waitcnt vmcnt(0)" ::: "memory");
        __syncthreads();   // inn m ready; h visible (m==0)

        f32x4 acc2[4][4] = {};
        #pragma unroll
        for (int kk = 0; kk < 2; ++kk) {
            short8 a[4], b2v[4];
            #pragma unroll
            for (int mi = 0; mi < 4; ++mi) {
                int tok = wm * 64 + mi * 16 + lr;
                a[mi] = *(const short8*)(smem + tok * 256 + ((wn * 64 + kk * 32 + lk) ^ ((tok & 7) << 3)));
            }
            #pragma unroll
            for (int ni = 0; ni < 4; ++ni) {
                int y = ni * 16 + lr;
                b2v[ni] = *(const short8*)(inn + wn * 4096 + y * 64 + ((kk * 32 + lk) ^ ((y & 7) << 3)));
            }
            #pragma unroll
            for (int mi = 0; mi < 4; ++mi)
                #pragma unroll
                for (int ni = 0; ni < 4; ++ni)   // swapped: D=[y][tok]
                    acc2[mi][ni] = __builtin_amdgcn_mfma_f32_16x16x32_bf16(b2v[ni], a[mi], acc2[mi][ni], 0, 0, 0);
        }

        const int kp = (i0 + wn) * 4 + m;
        #pragma unroll
        for (int mi = 0; mi < 4; ++mi) {
            int tok = m0 + wm * 64 + mi * 16 + lr;
            unsigned short* trow = T + ((size_t)tok * KMID + kp) * 64;
            #pragma unroll
            for (int ni = 0; ni < 4; ++ni) {
                int y0 = ni * 16 + hi * 4;
                US4 o;
                #pragma unroll
                for (int j = 0; j < 4; ++j) o.v[j] = f2bf(acc2[mi][ni][j]);
                *(US4*)(trow + y0) = o;
            }
        }
        __syncthreads();   // protect inn before next m's DMA
    }
    #undef RD_A
    #undef RD_B
    #undef MF
    #undef PHASE_TAIL
    #undef PHASE_END
}

// ---------------- stage 3 (r7 structure): out[b][o][y] = sum_k Ob[o][k] t[b][k][y]
__global__ __launch_bounds__(512) void stage3(
    const unsigned short* __restrict__ T,   // [2048][256][64] bf16
    const unsigned short* __restrict__ Ob,  // [1024][256] bf16
    float* __restrict__ out)                // [2048][65536] f32
{
    __shared__ char ts[32768];
    const int tid = threadIdx.x;
    const int lane = tid & 63;
    const int w = tid >> 6;
    int bx = blockIdx.x;
    const int b = (bx & 7) * 256 + (bx >> 3);   // XCD swizzle
    const int lr = lane & 15;
    const int hi = lane >> 4;

    {
        const unsigned short* src = T + (size_t)b * (KMID * 64);
        #pragma unroll
        for (int c = 0; c < 4; ++c) {
            int e = c * 4096 + tid * 8;
            int k = e >> 6, y = e & 63;
            short8 v = __builtin_nontemporal_load((const short8*)(src + e));
            #pragma unroll
            for (int j = 0; j < 8; ++j)
                *(unsigned short*)(ts + SWZ(y + j, k)) = (unsigned short)v[j];
        }
    }
    __syncthreads();

    const int o_base = w * 128;
    f32x4 acc[4][8] = {};   // [ni_y][mi_o]
    for (int kt = 0; kt < 8; ++kt) {
        short8 tf[4], of[8];
        #pragma unroll
        for (int ni = 0; ni < 4; ++ni)
            tf[ni] = *(const short8*)(ts + SWZ(ni * 16 + lr, kt * 32 + hi * 8));
        #pragma unroll
        for (int mi = 0; mi < 8; ++mi)
            of[mi] = *(const short8*)(Ob + ((size_t)(o_base + mi * 16 + lr) << 8) + kt * 32 + hi * 8);
        #pragma unroll
        for (int ni = 0; ni < 4; ++ni)
            #pragma unroll
            for (int mi = 0; mi < 8; ++mi)
                acc[ni][mi] = __builtin_amdgcn_mfma_f32_16x16x32_bf16(tf[ni], of[mi], acc[ni][mi], 0, 0, 0);
    }

    float* ob = out + (size_t)b * NUM_LATENTS;
    #pragma unroll
    for (int ni = 0; ni < 4; ++ni) {
        #pragma unroll
        for (int mi = 0; mi < 8; ++mi) {
            int o = o_base + mi * 16 + lr;
            int y = ni * 16 + hi * 4;
            __builtin_nontemporal_store(acc[ni][mi], (f32x4*)(ob + (o << 6) + y));
        }
    }
}

extern "C" void kernel_launch(void* const* d_in, const int* in_sizes, int n_in,
                              void* d_out, int out_size, void* d_ws, size_t ws_size,
                              hipStream_t stream) {
    const float* x     = (const float*)d_in[0];
    const float* pre_w = (const float*)d_in[1];
    const float* pre_b = (const float*)d_in[2];
    const float* inner = (const float*)d_in[3];
    const float* outer = (const float*)d_in[4];
    float* out = (float*)d_out;

    char* ws = (char*)d_ws;
    unsigned short* x_bf = (unsigned short*)ws;  ws += (size_t)TOKENS * D_IN * 2;
    unsigned short* w_bf = (unsigned short*)ws;  ws += (size_t)D_IN * D_IN * 2;
    unsigned short* o_bf = (unsigned short*)ws;  ws += (size_t)1024 * KMID * 2;
    unsigned short* t_bf = (unsigned short*)ws;  ws += (size_t)TOKENS * KMID * 64 * 2;
    unsigned short* it_bf = (unsigned short*)ws; ws += (size_t)GROUP_MUL * IN_GROUPS * 64 * 64 * 2;

    cvt_all<<<FLAT_BLOCKS + GROUP_MUL * IN_GROUPS, 256, 0, stream>>>(
        pre_w, x, outer, inner, w_bf, x_bf, o_bf, it_bf);

    gemm_fused<<<256, 512, 0, stream>>>(x_bf, w_bf, pre_b, it_bf, t_bf);
    stage3<<<2048, 512, 0, stream>>>(t_bf, o_bf, out);
}

// Round 13
// 313.781 us; speedup vs baseline: 1.4951x; 1.0050x over previous
//
#include <hip/hip_runtime.h>
#include <hip/hip_bf16.h>
#include <stdint.h>

#define D_IN 4096
#define TOKENS 2048
#define NUM_LATENTS 65536
#define GROUP_MUL 4
#define IN_GROUPS 64
#define KMID 256   // k' = i*4 + m

typedef __attribute__((ext_vector_type(8))) short short8;
typedef __attribute__((ext_vector_type(4))) float f32x4;

struct alignas(8)  US4 { unsigned short v[4]; };

#define FLAT_BLOCKS 24832   // (4194304 + 2097152 + 65536) / 256

__device__ inline unsigned short f2bf(float f) {
    union { float f; unsigned u; } w{f};
    unsigned r = w.u + 0x7fffu + ((w.u >> 16) & 1u);  // RNE
    return (unsigned short)(r >> 16);
}

__device__ inline void gload_lds16(const void* g, void* l) {
    __builtin_amdgcn_global_load_lds(
        (const __attribute__((address_space(1))) void*)g,
        (__attribute__((address_space(3))) void*)l, 16, 0, 0);
}

// stage3 LDS swizzle: [y][k] bf16 rows of 512B.
__device__ inline int SWZ(int y, int k) {
    return ((y << 9) + (k << 1)) ^ ((((y & 7) ^ ((y >> 3) & 7)) << 4));
}

// ------------- merged converts: w, x (vector), outer (perm), inner (transpose)
__global__ __launch_bounds__(256) void cvt_all(
    const float* __restrict__ w, const float* __restrict__ x,
    const float* __restrict__ outer, const float* __restrict__ inner,
    unsigned short* __restrict__ w_bf, unsigned short* __restrict__ x_bf,
    unsigned short* __restrict__ o_bf, unsigned short* __restrict__ it_bf) {
    __shared__ float tl[64][65];
    int blk = blockIdx.x;
    const int tid = threadIdx.x;
    if (blk >= FLAT_BLOCKS) {
        // inner[m][i][x][y] f32 -> innT[m][i][y][x^((y&7)<<3)] bf16 (pre-swizzled)
        blk -= FLAT_BLOCKS;                  // m*64+i
        const float* src = inner + (size_t)blk * 4096;
        #pragma unroll
        for (int p = 0; p < 4; ++p) {
            int idx = p * 1024 + tid * 4;
            int xx = idx >> 6, y = idx & 63;
            f32x4 v = *(const f32x4*)(src + idx);
            #pragma unroll
            for (int j = 0; j < 4; ++j) tl[xx][y + j] = v[j];
        }
        __syncthreads();
        unsigned short* dst = it_bf + (size_t)blk * 4096;
        #pragma unroll
        for (int p = 0; p < 4; ++p) {
            int idx = p * 1024 + tid * 4;
            int y = idx >> 6, x0 = idx & 63;
            US4 o;
            #pragma unroll
            for (int j = 0; j < 4; ++j) o.v[j] = f2bf(tl[x0 + j][y]);
            *(US4*)(dst + y * 64 + (x0 ^ ((y & 7) << 3))) = o;
        }
        return;
    }
    int s = blk * 256 + tid;                 // f32x4 slot
    if (s < 4194304) {                       // w
        f32x4 v = *(const f32x4*)(w + (size_t)s * 4);
        US4 o;
        #pragma unroll
        for (int j = 0; j < 4; ++j) o.v[j] = f2bf(v[j]);
        *(US4*)(w_bf + (size_t)s * 4) = o;
    } else if (s < 6291456) {                // x
        int t = s - 4194304;
        f32x4 v = *(const f32x4*)(x + (size_t)t * 4);
        US4 o;
        #pragma unroll
        for (int j = 0; j < 4; ++j) o.v[j] = f2bf(v[j]);
        *(US4*)(x_bf + (size_t)t * 4) = o;
    } else {                                 // outer: [o][m][i] -> [o][i*4+m]
        int t0 = (s - 6291456) * 4;
        int o = t0 >> 8, r = t0 & 255, m = r >> 6, i = r & 63;
        f32x4 v = *(const f32x4*)(outer + t0);
        #pragma unroll
        for (int j = 0; j < 4; ++j)
            o_bf[(o << 8) + (i + j) * 4 + m] = f2bf(v[j]);
    }
}

// ------- fused stage 1+2, 8-PHASE schedule (T2+T3+T4+T5) -------------------
// BM=128 BN=256 BK=64, grid 256 (1 block/CU), 512 thr = 8 waves (2Mx4N).
__global__ __launch_bounds__(512, 2) void gemm_fused(
    const unsigned short* __restrict__ A,   // x_bf  [2048][4096]
    const unsigned short* __restrict__ B,   // w_bf  [4096][4096]
    const float* __restrict__ bias,
    const unsigned short* __restrict__ IT,  // innT [4][64][64][64] bf16, x pre-swizzled
    unsigned short* __restrict__ T)         // [2048][256][64] bf16
{
    __shared__ unsigned short smem[49152];  // 96 KB

    const int tid = threadIdx.x;
    const int lane = tid & 63;
    const int w = tid >> 6;          // 0..7
    const int wm = w >> 2;           // 0..1 : 64-token half
    const int wn = w & 3;            // 0..3 : 64-col quarter of 256
    int bx = blockIdx.x;
    const int logical = (bx & 7) * 32 + (bx >> 3);  // XCD x -> n-tiles {2x,2x+1}
    const int m0 = (logical & 15) * 128;
    const int n0 = (logical >> 4) * 256;
    const int i0 = n0 >> 6;          // first of 4 i-groups

    const int lr = lane & 15;
    const int hi = lane >> 4;
    const int lk = hi * 8;

    f32x4 acc[4][4] = {};

    auto STAGE_A = [&](unsigned short* As, int k0) {
        #pragma unroll
        for (int c = 0; c < 2; ++c) {
            int f = c * 4096 + tid * 8;
            int r = f >> 6;
            int colsw = ((((f >> 3) & 7) ^ (r & 7)) << 3);
            gload_lds16(A + (size_t)(m0 + r) * D_IN + k0 + colsw, As + f);
        }
    };
    auto STAGE_B = [&](unsigned short* Bs, int k0, int c0) {
        #pragma unroll
        for (int c = 0; c < 2; ++c) {
            int f = (c0 + c) * 4096 + tid * 8;
            int r = f >> 6;
            int colsw = ((((f >> 3) & 7) ^ (r & 7)) << 3);
            gload_lds16(B + (size_t)(n0 + r) * D_IN + k0 + colsw, Bs + f);
        }
    };

    STAGE_A(smem, 0);
    STAGE_B(smem + 8192, 0, 0);
    STAGE_B(smem + 8192, 0, 2);

    short8 a0, a1, a2, a3, b0, b1, b2, b3;
    #define RD_A(dst, mi, kk, as) { int row = wm * 64 + (mi) * 16 + lr; \
        dst = *(const short8*)((as) + (row << 6) + ((((kk << 2) + hi) ^ (lr & 7)) << 3)); }
    #define RD_B(dst, ni, kk, bs) { int row = wn * 64 + (ni) * 16 + lr; \
        dst = *(const short8*)((bs) + (row << 6) + ((((kk << 2) + hi) ^ (lr & 7)) << 3)); }
    #define MF(mi, ni, bb, aa) acc[mi][ni] = __builtin_amdgcn_mfma_f32_16x16x32_bf16(bb, aa, acc[mi][ni], 0, 0, 0);
    #define PHASE_TAIL \
        __builtin_amdgcn_s_barrier(); \
        asm volatile("s_waitcnt lgkmcnt(0)" ::: "memory"); \
        __builtin_amdgcn_sched_barrier(0);
    #define PHASE_END \
        __builtin_amdgcn_s_setprio(0); \
        __builtin_amdgcn_s_barrier(); \
        __builtin_amdgcn_sched_barrier(0);

    #pragma unroll 1
    for (int t = 0; t < 64; ++t) {
        unsigned short* As = smem + (t & 1) * 24576;
        unsigned short* Bs = As + 8192;
        unsigned short* Asn = smem + ((t & 1) ^ 1) * 24576;
        unsigned short* Bsn = Asn + 8192;
        const int kn = (t + 1) * 64;

        asm volatile("s_waitcnt vmcnt(0)" ::: "memory");
        __builtin_amdgcn_s_barrier();
        __builtin_amdgcn_sched_barrier(0);

        if (t < 63) STAGE_A(Asn, kn);
        RD_A(a0, 0, 0, As) RD_A(a1, 1, 0, As) RD_A(a2, 2, 0, As) RD_A(a3, 3, 0, As)
        RD_B(b0, 0, 0, Bs) RD_B(b1, 1, 0, Bs)
        PHASE_TAIL
        __builtin_amdgcn_s_setprio(1);
        MF(0,0,b0,a0) MF(1,0,b0,a1) MF(2,0,b0,a2) MF(3,0,b0,a3)
        MF(0,1,b1,a0) MF(1,1,b1,a1) MF(2,1,b1,a2) MF(3,1,b1,a3)
        PHASE_END

        if (t < 63) STAGE_B(Bsn, kn, 0);
        RD_B(b2, 2, 0, Bs) RD_B(b3, 3, 0, Bs)
        PHASE_TAIL
        __builtin_amdgcn_s_setprio(1);
        MF(0,2,b2,a0) MF(1,2,b2,a1) MF(2,2,b2,a2) MF(3,2,b2,a3)
        MF(0,3,b3,a0) MF(1,3,b3,a1) MF(2,3,b3,a2) MF(3,3,b3,a3)
        PHASE_END

        if (t < 63) STAGE_B(Bsn, kn, 2);
        RD_A(a0, 0, 1, As) RD_A(a1, 1, 1, As) RD_A(a2, 2, 1, As) RD_A(a3, 3, 1, As)
        RD_B(b0, 0, 1, Bs) RD_B(b1, 1, 1, Bs)
        PHASE_TAIL
        __builtin_amdgcn_s_setprio(1);
        MF(0,0,b0,a0) MF(1,0,b0,a1) MF(2,0,b0,a2) MF(3,0,b0,a3)
        MF(0,1,b1,a0) MF(1,1,b1,a1) MF(2,1,b1,a2) MF(3,1,b1,a3)
        PHASE_END

        RD_B(b2, 2, 1, Bs) RD_B(b3, 3, 1, Bs)
        PHASE_TAIL
        __builtin_amdgcn_s_setprio(1);
        MF(0,2,b2,a0) MF(1,2,b2,a1) MF(2,2,b2,a2) MF(3,2,b2,a3)
        MF(0,3,b3,a0) MF(1,3,b3,a1) MF(2,3,b3,a2) MF(3,3,b3,a3)
        PHASE_END
    }

    // ---- epilogue A: h (+bias, bf16) -> smem[0..32767], swizzled (512B rows)
    #pragma unroll
    for (int ni = 0; ni < 4; ++ni) {
        int col0 = wn * 64 + ni * 16 + hi * 4;
        f32x4 bv = *(const f32x4*)(bias + n0 + col0);
        #pragma unroll
        for (int mi = 0; mi < 4; ++mi) {
            int tok = wm * 64 + mi * 16 + lr;
            US4 o;
            #pragma unroll
            for (int j = 0; j < 4; ++j) o.v[j] = f2bf(acc[mi][ni][j] + bv[j]);
            *(US4*)(smem + tok * 256 + (col0 ^ ((tok & 7) << 3))) = o;
        }
    }

    // ---- epilogue B: per m, wave wn owns i-group i0+wn
    unsigned short* inn = smem + 32768;    // 4 x 4096 elems = 32 KB
    for (int m = 0; m < 4; ++m) {
        #pragma unroll
        for (int c = 0; c < 4; ++c) {
            int e = c * 4096 + tid * 8;
            int i_l = e >> 12, rem = e & 4095;
            gload_lds16(IT + ((size_t)(m * 64 + i0 + i_l) << 12) + rem, inn + e);
        }
        asm volatile("s_waitcnt vmcnt(0)" ::: "memory");
        __syncthreads();

        f32x4 acc2[4][4] = {};
        #pragma unroll
        for (int kk = 0; kk < 2; ++kk) {
            short8 a[4], b2v[4];
            #pragma unroll
            for (int mi = 0; mi < 4; ++mi) {
                int tok = wm * 64 + mi * 16 + lr;
                a[mi] = *(const short8*)(smem + tok * 256 + ((wn * 64 + kk * 32 + lk) ^ ((tok & 7) << 3)));
            }
            #pragma unroll
            for (int ni = 0; ni < 4; ++ni) {
                int y = ni * 16 + lr;
                b2v[ni] = *(const short8*)(inn + wn * 4096 + y * 64 + ((kk * 32 + lk) ^ ((y & 7) << 3)));
            }
            #pragma unroll
            for (int mi = 0; mi < 4; ++mi)
                #pragma unroll
                for (int ni = 0; ni < 4; ++ni)   // swapped: D=[y][tok]
                    acc2[mi][ni] = __builtin_amdgcn_mfma_f32_16x16x32_bf16(b2v[ni], a[mi], acc2[mi][ni], 0, 0, 0);
        }

        const int kp = (i0 + wn) * 4 + m;
        #pragma unroll
        for (int mi = 0; mi < 4; ++mi) {
            int tok = m0 + wm * 64 + mi * 16 + lr;
            unsigned short* trow = T + ((size_t)tok * KMID + kp) * 64;
            #pragma unroll
            for (int ni = 0; ni < 4; ++ni) {
                int y0 = ni * 16 + hi * 4;
                US4 o;
                #pragma unroll
                for (int j = 0; j < 4; ++j) o.v[j] = f2bf(acc2[mi][ni][j]);
                *(US4*)(trow + y0) = o;
            }
        }
        __syncthreads();
    }
    #undef RD_A
    #undef RD_B
    #undef MF
    #undef PHASE_TAIL
    #undef PHASE_END
}

// ------- stage 3, PERSISTENT: out[b][o][y] = sum_k Ob[o][k] t[b][k][y] -----
// grid 256 (1 block/CU) x 512 thr; each block owns 8 consecutive tokens.
// Double-buffered ts (2x32KB). Per iter: issue next-T loads (oldest vmem) ->
// compute+store current (store drain overlaps next iters) -> ds_write -> bar.
__global__ __launch_bounds__(512, 1) void stage3(
    const unsigned short* __restrict__ T,   // [2048][256][64] bf16
    const unsigned short* __restrict__ Ob,  // [1024][256] bf16
    float* __restrict__ out)                // [2048][65536] f32
{
    __shared__ char ts[65536];              // 2 x 32 KB
    const int tid = threadIdx.x;
    const int lane = tid & 63;
    const int w = tid >> 6;
    const int bx = blockIdx.x;
    const int b0 = ((bx & 7) * 32 + (bx >> 3)) * 8;   // 8 consecutive tokens, XCD-local
    const int lr = lane & 15;
    const int hi = lane >> 4;
    const int o_base = w * 128;

    short8 pre[4];
    // prologue: token b0 -> regs -> ts[0]
    {
        const unsigned short* src = T + (size_t)b0 * (KMID * 64);
        #pragma unroll
        for (int c = 0; c < 4; ++c)
            pre[c] = __builtin_nontemporal_load((const short8*)(src + c * 4096 + tid * 8));
        #pragma unroll
        for (int c = 0; c < 4; ++c) {
            int e = c * 4096 + tid * 8;
            int k = e >> 6, y = e & 63;
            #pragma unroll
            for (int j = 0; j < 8; ++j)
                *(unsigned short*)(ts + SWZ(y + j, k)) = (unsigned short)pre[c][j];
        }
    }
    __syncthreads();

    int cur = 0;
    #pragma unroll 1
    for (int it = 0; it < 8; ++it) {
        const int b = b0 + it;

        // prefetch next token's T into regs (oldest vmem ops; retired by the
        // time the first of-load wait fires -> zero extra stall)
        if (it < 7) {
            const unsigned short* src = T + (size_t)(b + 1) * (KMID * 64);
            #pragma unroll
            for (int c = 0; c < 4; ++c)
                pre[c] = __builtin_nontemporal_load((const short8*)(src + c * 4096 + tid * 8));
        }

        // compute token b from ts[cur]
        const char* tsc = ts + cur * 32768;
        f32x4 acc[4][8] = {};   // [ni_y][mi_o]
        #pragma unroll 1
        for (int kt = 0; kt < 8; ++kt) {
            short8 tf[4], of[8];
            #pragma unroll
            for (int ni = 0; ni < 4; ++ni)
                tf[ni] = *(const short8*)(tsc + SWZ(ni * 16 + lr, kt * 32 + hi * 8));
            #pragma unroll
            for (int mi = 0; mi < 8; ++mi)
                of[mi] = *(const short8*)(Ob + ((size_t)(o_base + mi * 16 + lr) << 8) + kt * 32 + hi * 8);
            #pragma unroll
            for (int ni = 0; ni < 4; ++ni)
                #pragma unroll
                for (int mi = 0; mi < 8; ++mi)
                    acc[ni][mi] = __builtin_amdgcn_mfma_f32_16x16x32_bf16(tf[ni], of[mi], acc[ni][mi], 0, 0, 0);
        }

        // stores (nontemporal; drain overlaps subsequent iterations)
        float* ob = out + (size_t)b * NUM_LATENTS;
        #pragma unroll
        for (int ni = 0; ni < 4; ++ni) {
            #pragma unroll
            for (int mi = 0; mi < 8; ++mi) {
                int o = o_base + mi * 16 + lr;
                int y = ni * 16 + hi * 4;
                __builtin_nontemporal_store(acc[ni][mi], (f32x4*)(ob + (o << 6) + y));
            }
        }

        // stage next token into the other buffer (safe: nobody reads it now)
        if (it < 7) {
            char* tsn = ts + (cur ^ 1) * 32768;
            #pragma unroll
            for (int c = 0; c < 4; ++c) {
                int e = c * 4096 + tid * 8;
                int k = e >> 6, y = e & 63;
                #pragma unroll
                for (int j = 0; j < 8; ++j)
                    *(unsigned short*)(tsn + SWZ(y + j, k)) = (unsigned short)pre[c][j];
            }
            __syncthreads();
            cur ^= 1;
        }
    }
}

extern "C" void kernel_launch(void* const* d_in, const int* in_sizes, int n_in,
                              void* d_out, int out_size, void* d_ws, size_t ws_size,
                              hipStream_t stream) {
    const float* x     = (const float*)d_in[0];
    const float* pre_w = (const float*)d_in[1];
    const float* pre_b = (const float*)d_in[2];
    const float* inner = (const float*)d_in[3];
    const float* outer = (const float*)d_in[4];
    float* out = (float*)d_out;

    char* ws = (char*)d_ws;
    unsigned short* x_bf = (unsigned short*)ws;  ws += (size_t)TOKENS * D_IN * 2;
    unsigned short* w_bf = (unsigned short*)ws;  ws += (size_t)D_IN * D_IN * 2;
    unsigned short* o_bf = (unsigned short*)ws;  ws += (size_t)1024 * KMID * 2;
    unsigned short* t_bf = (unsigned short*)ws;  ws += (size_t)TOKENS * KMID * 64 * 2;
    unsigned short* it_bf = (unsigned short*)ws; ws += (size_t)GROUP_MUL * IN_GROUPS * 64 * 64 * 2;

    cvt_all<<<FLAT_BLOCKS + GROUP_MUL * IN_GROUPS, 256, 0, stream>>>(
        pre_w, x, outer, inner, w_bf, x_bf, o_bf, it_bf);

    gemm_fused<<<256, 512, 0, stream>>>(x_bf, w_bf, pre_b, it_bf, t_bf);
    stage3<<<256, 512, 0, stream>>>(t_bf, o_bf, out);
}